// Round 6
// baseline (384.410 us; speedup 1.0000x reference)
//
#include <hip/hip_runtime.h>

// Problem constants (fixed by the reference)
#define Bn   4
#define Tn   512
#define Pn   3
#define HIDn 512
#define HDn  32
#define Hn   16
#define EXPn 512
#define Sn   1024
#define Dn   96          // per-head dim = P*HD
#define LOG2E 1.44269504088896340736f

typedef __bf16 bf16_t;
typedef __bf16 bf16x8 __attribute__((ext_vector_type(8)));
typedef float  f32x4  __attribute__((ext_vector_type(4)));

// ---------------------------------------------------------------------------
// pack_qk (R3/R4/R5-verified)
// ---------------------------------------------------------------------------
__global__ __launch_bounds__(192) void pack_qk(
    const float* __restrict__ q, const float* __restrict__ k,
    const int* __restrict__ outcell,
    bf16_t* __restrict__ Qh, bf16_t* __restrict__ Kh)
{
    const int bs = blockIdx.x;
    const int b = bs >> 10, s = bs & 1023;
    const int ts = (s < Tn) ? s : outcell[b * EXPn + (s - Tn)];
    const int o = threadIdx.x;            // 0..191
    const int h = o / 12, c = o % 12;
    const int p = c >> 2, f = c & 3;
    const int src = p * HIDn + h * HDn + f * 8;

    {
        const float* krow = k + (size_t)(b * Tn + ts) * (Pn * HIDn);
        const float4* s4 = (const float4*)(krow + src);
        float4 f0 = s4[0], f1 = s4[1];
        bf16_t o8[8] = {(bf16_t)f0.x, (bf16_t)f0.y, (bf16_t)f0.z, (bf16_t)f0.w,
                        (bf16_t)f1.x, (bf16_t)f1.y, (bf16_t)f1.z, (bf16_t)f1.w};
        *(uint4*)&Kh[(((size_t)b * Hn + h) * Sn + s) * Dn + c * 8] = *(uint4*)o8;
    }
    if (s < Tn) {
        const float* qrow = q + (size_t)(b * Tn + s) * (Pn * HIDn);
        const float4* s4 = (const float4*)(qrow + src);
        float4 f0 = s4[0], f1 = s4[1];
        bf16_t o8[8] = {(bf16_t)f0.x, (bf16_t)f0.y, (bf16_t)f0.z, (bf16_t)f0.w,
                        (bf16_t)f1.x, (bf16_t)f1.y, (bf16_t)f1.z, (bf16_t)f1.w};
        *(uint4*)&Qh[(((size_t)b * Hn + h) * Tn + s) * Dn + c * 8] = *(uint4*)o8;
    }
}

// ---------------------------------------------------------------------------
// pack_v (R3/R4/R5-verified)
// ---------------------------------------------------------------------------
__global__ __launch_bounds__(256) void pack_v(
    const float* __restrict__ v, const int* __restrict__ outcell,
    bf16_t* __restrict__ Vt)
{
    const int blk = blockIdx.x;
    const int bh = blk >> 4, s0 = (blk & 15) << 6;
    const int b = bh >> 4, h = bh & 15;
    __shared__ float tile[64 * 108];
    __shared__ int ts_sh[64];
    if (threadIdx.x < 64) {
        const int s = s0 + threadIdx.x;
        ts_sh[threadIdx.x] = (s < Tn) ? s : outcell[b * EXPn + (s - Tn)];
    }
    __syncthreads();
    for (int u = threadIdx.x; u < 64 * 24; u += 256) {
        const int sl = u / 24, c = u % 24;
        const int p = c >> 3, f = c & 7;
        float4 val = *(const float4*)&v[(size_t)(b * Tn + ts_sh[sl]) * (Pn * HIDn)
                                        + p * HIDn + h * HDn + f * 4];
        *(float4*)&tile[sl * 108 + c * 4] = val;
    }
    __syncthreads();
    for (int e = threadIdx.x; e < 96 * 8; e += 256) {
        const int d = e >> 3, g = e & 7;
        bf16_t o8[8];
#pragma unroll
        for (int j = 0; j < 8; ++j) o8[j] = (bf16_t)tile[(g * 8 + j) * 108 + d];
        *(uint4*)&Vt[((size_t)bh * Dn + d) * Sn + s0 + g * 8] = *(uint4*)o8;
    }
}

// ---------------------------------------------------------------------------
// pack_w (verified)
// ---------------------------------------------------------------------------
__global__ __launch_bounds__(256) void pack_w(
    const float* __restrict__ W, bf16_t* __restrict__ Wb)
{
    const int i = blockIdx.x * 256 + threadIdx.x;
    float4 f0 = *(const float4*)&W[i * 8];
    float4 f1 = *(const float4*)&W[i * 8 + 4];
    bf16_t o8[8] = {(bf16_t)f0.x, (bf16_t)f0.y, (bf16_t)f0.z, (bf16_t)f0.w,
                    (bf16_t)f1.x, (bf16_t)f1.y, (bf16_t)f1.z, (bf16_t)f1.w};
    *(uint4*)&Wb[i * 8] = *(uint4*)o8;
}

// ---------------------------------------------------------------------------
// attn_kernel: IN-BLOCK S-SPLIT flash attention.  Block = 16 t-rows; each of
// the 4 waves runs the R5-verified per-chunk pipeline over one S-quarter
// (4 chunks of 64).  4x the blocks (2048) -> 8 waves/SIMD offered vs R5's 2.
// Partials (unnormalized O, m, l) merge in LDS after one barrier:
//   gm = max_q m_q;  wq = exp2(m_q-gm);  O = sum wq*O_q / sum wq*l_q.
// Ps overlays the wave's Om region (last Ps read precedes first Om write,
// same wave).  Om row stride 100 floats (100%32=4) kills merge bank
// conflicts.  Zero extra HBM traffic vs R5.
// ---------------------------------------------------------------------------
__global__ __launch_bounds__(256, 4) void attn_kernel(
    const bf16_t* __restrict__ Qh, const bf16_t* __restrict__ Kh,
    const bf16_t* __restrict__ Vt, const float* __restrict__ bias,
    const float* __restrict__ lw, float* __restrict__ attn_out,
    float* __restrict__ sumsq)
{
    const int h  = blockIdx.x;
    const int b  = blockIdx.y >> 5;
    const int t0 = (blockIdx.y & 31) << 4;      // 16 t-rows per block
    const int tid = threadIdx.x;
    const int wv  = tid >> 6;
    const int lane = tid & 63;
    const int l16 = lane & 15;
    const int quad = lane >> 4;

    __shared__ float Om[4 * 16 * 100];          // per-wave partial O (stride 100)
    __shared__ float ml[4][16][2];              // per-wave (m, l) per row
    bf16_t* Psw = (bf16_t*)&Om[wv * 1600];      // wave-private P buffer (overlay)

    const size_t bh = (size_t)b * Hn + h;
    const int qs = wv << 8;                     // this wave's S-quarter start

    // Q A-fragments (same 16 rows for all 4 waves)
    bf16x8 qf[3];
    {
        const bf16_t* qb = Qh + (bh * Tn + t0 + l16) * Dn + quad * 8;
#pragma unroll
        for (int ks = 0; ks < 3; ++ks) qf[ks] = *(const bf16x8*)(qb + ks * 32);
    }

    const bf16_t* kbase = Kh + (bh * Sn + l16) * Dn + quad * 8;
    const bf16_t* vbase = Vt + (bh * Dn + l16) * Sn + quad * 8;
    const float*  bbase = bias + ((bh * Tn + t0 + quad * 4)) * (size_t)Sn + l16;
    const float*  lbase = lw + (((size_t)b * Tn + t0 + quad * 4)) * Sn + l16;

    f32x4 Oacc[6];
#pragma unroll
    for (int i = 0; i < 6; ++i) Oacc[i] = f32x4{0.f, 0.f, 0.f, 0.f};
    float mrow[4], lrow[4];
#pragma unroll
    for (int r = 0; r < 4; ++r) { mrow[r] = -3.0e38f; lrow[r] = 0.f; }

    // prologue: bias/lw for this wave's chunk 0
    float BRc[16], LRc[16], BRn[16], LRn[16];
#pragma unroll
    for (int ct = 0; ct < 4; ++ct)
#pragma unroll
        for (int r = 0; r < 4; ++r) {
            BRc[ct * 4 + r] = bbase[(size_t)r * Sn + qs + ct * 16];
            LRc[ct * 4 + r] = lbase[(size_t)r * Sn + qs + ct * 16];
        }

    for (int c = 0; c < 4; ++c) {
        const int s0 = qs + c * 64;
        // ---- current chunk's K B-frags (L2-resident)
        bf16x8 kf[4][3];
#pragma unroll
        for (int ct = 0; ct < 4; ++ct)
#pragma unroll
            for (int ks = 0; ks < 3; ++ks)
                kf[ct][ks] = *(const bf16x8*)(kbase + (size_t)(s0 + ct * 16) * Dn + ks * 32);

        // ---- NEXT chunk's bias/lw (HBM stream; consumed next iter)
        const int s0n = qs + (((c + 1) & 3) << 6);   // wrap inside quarter: harmless
#pragma unroll
        for (int ct = 0; ct < 4; ++ct)
#pragma unroll
            for (int r = 0; r < 4; ++r) {
                BRn[ct * 4 + r] = bbase[(size_t)r * Sn + s0n + ct * 16];
                LRn[ct * 4 + r] = lbase[(size_t)r * Sn + s0n + ct * 16];
            }

        // ---- QK^T
        f32x4 sc[4];
#pragma unroll
        for (int ct = 0; ct < 4; ++ct) {
            f32x4 acc = f32x4{0.f, 0.f, 0.f, 0.f};
#pragma unroll
            for (int ks = 0; ks < 3; ++ks)
                acc = __builtin_amdgcn_mfma_f32_16x16x32_bf16(qf[ks], kf[ct][ks], acc, 0, 0, 0);
            sc[ct] = acc;
        }

        // ---- + bias, lw-cutoff mask, chunk row-max
        float cmax[4] = {-3.0e38f, -3.0e38f, -3.0e38f, -3.0e38f};
#pragma unroll
        for (int ct = 0; ct < 4; ++ct) {
#pragma unroll
            for (int r = 0; r < 4; ++r) {
                float wval = sc[ct][r] + BRc[ct * 4 + r];
                wval = (LRc[ct * 4 + r] <= 1e-5f) ? -3.0e38f : wval;
                sc[ct][r] = wval;
                cmax[r] = fmaxf(cmax[r], wval);
            }
        }
#pragma unroll
        for (int off = 1; off < 16; off <<= 1)
#pragma unroll
            for (int r = 0; r < 4; ++r)
                cmax[r] = fmaxf(cmax[r], __shfl_xor(cmax[r], off));

        // ---- online-softmax rescale
        float scl[4];
#pragma unroll
        for (int r = 0; r < 4; ++r) {
            const float mnew = fmaxf(mrow[r], cmax[r]);
            scl[r] = exp2f((mrow[r] - mnew) * LOG2E);
            mrow[r] = mnew;
            lrow[r] *= scl[r];
        }
#pragma unroll
        for (int dt = 0; dt < 6; ++dt)
#pragma unroll
            for (int r = 0; r < 4; ++r) Oacc[dt][r] *= scl[r];

        // ---- p = exp(w-m); l += p; stage (p*lw) bf16 in wave-private Ps
        float lsum[4] = {0.f, 0.f, 0.f, 0.f};
#pragma unroll
        for (int ct = 0; ct < 4; ++ct) {
#pragma unroll
            for (int r = 0; r < 4; ++r) {
                const float pe = exp2f((sc[ct][r] - mrow[r]) * LOG2E);
                lsum[r] += pe;
                Psw[(quad * 4 + r) * 72 + ct * 16 + l16] = (bf16_t)(pe * LRc[ct * 4 + r]);
            }
        }
#pragma unroll
        for (int off = 1; off < 16; off <<= 1)
#pragma unroll
            for (int r = 0; r < 4; ++r) lsum[r] += __shfl_xor(lsum[r], off);
#pragma unroll
        for (int r = 0; r < 4; ++r) lrow[r] += lsum[r];

        // ---- PV
        bf16x8 pa[2];
#pragma unroll
        for (int ks = 0; ks < 2; ++ks)
            pa[ks] = *(const bf16x8*)&Psw[l16 * 72 + ks * 32 + quad * 8];
#pragma unroll
        for (int dt = 0; dt < 6; ++dt) {
#pragma unroll
            for (int ks = 0; ks < 2; ++ks) {
                bf16x8 vf = *(const bf16x8*)(vbase + (size_t)(dt * 16) * Sn + s0 + ks * 32);
                Oacc[dt] = __builtin_amdgcn_mfma_f32_16x16x32_bf16(pa[ks], vf, Oacc[dt], 0, 0, 0);
            }
        }

        // ---- rotate bias/lw double-buffer
#pragma unroll
        for (int i = 0; i < 16; ++i) { BRc[i] = BRn[i]; LRc[i] = LRn[i]; }
    }

    // ---- publish this wave's partials (UNnormalized O, m, l)
    {
        float* OmW = &Om[wv * 1600];
#pragma unroll
        for (int dt = 0; dt < 6; ++dt)
#pragma unroll
            for (int r = 0; r < 4; ++r)
                OmW[(quad * 4 + r) * 100 + dt * 16 + l16] = Oacc[dt][r];
        if (l16 == 0) {
#pragma unroll
            for (int r = 0; r < 4; ++r) {
                ml[wv][quad * 4 + r][0] = mrow[r];
                ml[wv][quad * 4 + r][1] = lrow[r];
            }
        }
    }
    __syncthreads();

    // ---- merge 4 S-quarters: 16 threads per row, 6 elems each (d = eg+16j)
    {
        const int row = tid >> 4;
        const int eg  = tid & 15;
        float mq[4], lq[4];
#pragma unroll
        for (int qv = 0; qv < 4; ++qv) { mq[qv] = ml[qv][row][0]; lq[qv] = ml[qv][row][1]; }
        float gm = fmaxf(fmaxf(mq[0], mq[1]), fmaxf(mq[2], mq[3]));
        float wq[4], lstar = 0.f;
#pragma unroll
        for (int qv = 0; qv < 4; ++qv) {
            wq[qv] = exp2f((mq[qv] - gm) * LOG2E);
            lstar += wq[qv] * lq[qv];
        }
        const float invl = 1.0f / lstar;
        const int t = t0 + row;
        float ssl = 0.f;
#pragma unroll
        for (int j = 0; j < 6; ++j) {
            const int d = eg + 16 * j;
            float o = 0.f;
#pragma unroll
            for (int qv = 0; qv < 4; ++qv)
                o += wq[qv] * Om[qv * 1600 + row * 100 + d];
            o *= invl;
            ssl += o * o;
            const int p = d >> 5, hd = d & 31;
            attn_out[(((size_t)b * Tn + t) * Pn + p) * HIDn + h * HDn + hd] = o;
        }
#pragma unroll
        for (int off = 1; off < 16; off <<= 1) ssl += __shfl_xor(ssl, off);
        if (eg == 0) atomicAdd(&sumsq[b * Tn + t], ssl);
    }
}

// ---------------------------------------------------------------------------
// out_gemm (LN fused, R4/R5-verified)
// ---------------------------------------------------------------------------
__global__ __launch_bounds__(256, 2) void out_gemm(
    const float* __restrict__ attn, const float* __restrict__ sumsq,
    const float* __restrict__ lnwg, const bf16_t* __restrict__ Bw,
    float* __restrict__ out)
{
    const int n0 = blockIdx.x * 64;
    const int m0 = blockIdx.y * 64;
    const int tid = threadIdx.x;
    const int wv = tid >> 6, lane = tid & 63, l16 = lane & 15, quad = lane >> 4;
    __shared__ float lnw_s[HIDn];
    __shared__ float inv_s[64];
    __shared__ bf16_t As[2][64 * 72];
    __shared__ bf16_t Bs[2][64 * 72];

    for (int i = tid; i < HIDn; i += 256) lnw_s[i] = lnwg[i];
    if (tid < 64)
        inv_s[tid] = rsqrtf(sumsq[(m0 + tid) / 3] * (1.0f / HIDn) + 1e-3f);
    __syncthreads();

    const int rowA = tid >> 3, cA = tid & 7;
    const float inv0 = inv_s[rowA], inv1 = inv_s[rowA + 32];

    auto loadT = [&](int k0, float4 (&AF)[2][2], uint4 (&BR)[2], float4 (&LF)[2]) {
        LF[0] = *(const float4*)&lnw_s[k0 + cA * 8];
        LF[1] = *(const float4*)&lnw_s[k0 + cA * 8 + 4];
        AF[0][0] = *(const float4*)&attn[(size_t)(m0 + rowA) * HIDn + k0 + cA * 8];
        AF[0][1] = *(const float4*)&attn[(size_t)(m0 + rowA) * HIDn + k0 + cA * 8 + 4];
        AF[1][0] = *(const float4*)&attn[(size_t)(m0 + rowA + 32) * HIDn + k0 + cA * 8];
        AF[1][1] = *(const float4*)&attn[(size_t)(m0 + rowA + 32) * HIDn + k0 + cA * 8 + 4];
        BR[0] = *(const uint4*)&Bw[(size_t)(n0 + rowA) * HIDn + k0 + cA * 8];
        BR[1] = *(const uint4*)&Bw[(size_t)(n0 + rowA + 32) * HIDn + k0 + cA * 8];
    };
    auto storeT = [&](int buf, float4 (&AF)[2][2], uint4 (&BR)[2], float4 (&LF)[2]) {
#pragma unroll
        for (int j = 0; j < 2; ++j) {
            const float iv = j ? inv1 : inv0;
            bf16_t a8[8] = {(bf16_t)(AF[j][0].x * LF[0].x * iv), (bf16_t)(AF[j][0].y * LF[0].y * iv),
                            (bf16_t)(AF[j][0].z * LF[0].z * iv), (bf16_t)(AF[j][0].w * LF[0].w * iv),
                            (bf16_t)(AF[j][1].x * LF[1].x * iv), (bf16_t)(AF[j][1].y * LF[1].y * iv),
                            (bf16_t)(AF[j][1].z * LF[1].z * iv), (bf16_t)(AF[j][1].w * LF[1].w * iv)};
            *(uint4*)&As[buf][(rowA + j * 32) * 72 + cA * 8] = *(uint4*)a8;
            *(uint4*)&Bs[buf][(rowA + j * 32) * 72 + cA * 8] = BR[j];
        }
    };

    f32x4 acc[4];
#pragma unroll
    for (int i = 0; i < 4; ++i) acc[i] = f32x4{0.f, 0.f, 0.f, 0.f};

    float4 af0[2][2], af1[2][2], lf0[2], lf1[2];
    uint4 br0[2], br1[2];
    loadT(0, af0, br0, lf0);
    storeT(0, af0, br0, lf0);
    __syncthreads();

    auto compute = [&](int buf) {
#pragma unroll
        for (int ks = 0; ks < 2; ++ks) {
            bf16x8 a = *(const bf16x8*)&As[buf][(wv * 16 + l16) * 72 + ks * 32 + quad * 8];
#pragma unroll
            for (int nt = 0; nt < 4; ++nt) {
                bf16x8 bb = *(const bf16x8*)&Bs[buf][(nt * 16 + l16) * 72 + ks * 32 + quad * 8];
                acc[nt] = __builtin_amdgcn_mfma_f32_16x16x32_bf16(a, bb, acc[nt], 0, 0, 0);
            }
        }
    };

    for (int it = 0; it < 8; it += 2) {
        loadT((it + 1) * 64, af1, br1, lf1);
        compute(0);
        storeT(1, af1, br1, lf1);
        __syncthreads();
        const bool pf = (it + 2) < 8;
        if (pf) loadT((it + 2) * 64, af0, br0, lf0);
        compute(1);
        if (pf) storeT(0, af0, br0, lf0);
        __syncthreads();
    }
#pragma unroll
    for (int nt = 0; nt < 4; ++nt)
#pragma unroll
        for (int r = 0; r < 4; ++r) {
            const int m = m0 + wv * 16 + quad * 4 + r;
            const int n = n0 + nt * 16 + l16;
            out[(size_t)m * HIDn + n] = acc[nt][r];
        }
}

// ---------------------------------------------------------------------------
// Workspace: Qh@0 (6291456) | Kh@6291456 (12582912) | Vt@18874368 (12582912) |
// attn@31457280 (12582912) | Wb@44040192 (524288) | sumsq@44564480 (8192)
// ---------------------------------------------------------------------------
extern "C" void kernel_launch(void* const* d_in, const int* in_sizes, int n_in,
                              void* d_out, int out_size, void* d_ws, size_t ws_size,
                              hipStream_t stream)
{
    const float* q    = (const float*)d_in[0];
    const float* k    = (const float*)d_in[1];
    const float* v    = (const float*)d_in[2];
    const float* bias = (const float*)d_in[3];
    const int*   outcell = (const int*)d_in[5];
    const float* lw   = (const float*)d_in[6];
    const float* W    = (const float*)d_in[8];
    const float* lnw  = (const float*)d_in[9];
    float* out = (float*)d_out;

    char* ws = (char*)d_ws;
    bf16_t* Qh   = (bf16_t*)(ws);
    bf16_t* Kh   = (bf16_t*)(ws + 6291456);
    bf16_t* Vt   = (bf16_t*)(ws + 18874368);
    float*  attn = (float*)(ws + 31457280);
    bf16_t* Wb   = (bf16_t*)(ws + 44040192);
    float*  sumsq = (float*)(ws + 44564480);

    hipMemsetAsync(sumsq, 0, (Bn * Tn) * sizeof(float), stream);
    pack_qk<<<dim3(Bn * Sn), 192, 0, stream>>>(q, k, outcell, Qh, Kh);
    pack_v<<<dim3(Bn * Hn * 16), 256, 0, stream>>>(v, outcell, Vt);
    pack_w<<<dim3((HIDn * HIDn) / (256 * 8)), 256, 0, stream>>>(W, Wb);
    attn_kernel<<<dim3(Hn, Bn * (Tn / 16)), 256, 0, stream>>>(Qh, Kh, Vt, bias, lw, attn, sumsq);
    out_gemm<<<dim3(HIDn / 64, (Bn * Tn * Pn) / 64), 256, 0, stream>>>(attn, sumsq, lnw, Wb, out);
}